// Round 6
// baseline (920.094 us; speedup 1.0000x reference)
//
#include <hip/hip_runtime.h>

// GraphConv: out[t] += input[s] * (esgn*enorm), 3.2M edges, 100K nodes, D=32 fp32.
// Round 17: both tile partitions (R15 96us, R16 123us) were latency-bound
// shells: 544 blocks (grid-capped 26% occupancy), 23 serial edges/thread,
// per-block 1024-counter init + reservation. Ideal partition traffic ~130MB
// ~= 20us; we were 6x off on latency hiding alone. Fix: edge-parallel FLAT
// partition -- 4 edges/thread (int4/float4 loads), per edge one global
// atomicAdd on the bucket cursor (pre-seeded with scanned bases by bscan)
// and one direct 8B store. 800K threads hide all latency; in-bucket order is
// irrelevant (bucket_accum node-sorts in LDS). bhist/bscan/bucket_accum
// unchanged (verified). Pipeline: bhist -> bscan -> partition_flat -> bucket_accum.

#define NB   256
#define KMAX 1024         // max buckets (span 128 -> n_nodes <= 131072)
#define SPAN_SHIFT 7
#define SPAN 128
#define EPT  4            // edges per thread in partition_flat
#define CAP  6144         // bucket_accum LDS record capacity (48KB)

// Bucket-level histogram: LDS counters, one global atomic per bucket/block.
__global__ __launch_bounds__(NB) void bhist_kernel(
    const int* __restrict__ tidx, int* __restrict__ bcnt, int n_edges)
{
    __shared__ int lh[KMAX];
    for (int i = threadIdx.x; i < KMAX; i += NB) lh[i] = 0;
    __syncthreads();
    int stride = gridDim.x * NB;
    for (int e = blockIdx.x * NB + threadIdx.x; e < n_edges; e += stride)
        atomicAdd(&lh[tidx[e] >> SPAN_SHIFT], 1);
    __syncthreads();
    for (int i = threadIdx.x; i < KMAX; i += NB)
        if (lh[i]) atomicAdd(&bcnt[i], lh[i]);
}

// Exclusive scan over K (<=1024) bucket counts -> bbase[0..K], bcur0=bbase.
__global__ __launch_bounds__(1024) void bscan_kernel(
    const int* __restrict__ bcnt, int* __restrict__ bbase,
    int* __restrict__ bcur0, int K)
{
    __shared__ int part[KMAX];
    int t = threadIdx.x;
    int c = (t < K) ? bcnt[t] : 0;
    part[t] = c;
    __syncthreads();
    for (int off = 1; off < KMAX; off <<= 1) {
        int v = (t >= off) ? part[t - off] : 0;
        __syncthreads();
        part[t] += v;
        __syncthreads();
    }
    if (t < K) {
        int excl = part[t] - c;
        bbase[t] = excl;
        bcur0[t] = excl;      // absolute cursor: partition_flat needs no bbase read
    }
    if (t == K - 1) bbase[K] = part[t];
}

// R17 flat partition: 4 edges/thread, one global atomic + one 8B store per
// edge. No LDS, no tiles, no scan -- 800K independent threads.
#define DO_EDGE(tn_, sn_, w_) {                                              \
    int b_ = (tn_) >> SPAN_SHIFT;                                            \
    int pos_ = atomicAdd(&bcur0[b_], 1);                                     \
    unsigned rec_ = ((unsigned)(sn_) << SPAN_SHIFT) |                        \
                    (unsigned)((tn_) & (SPAN - 1));                          \
    recs[pos_] = make_int2((int)rec_, __float_as_int(w_)); }

__global__ __launch_bounds__(NB) void partition_flat(
    const int* __restrict__ sidx, const int* __restrict__ tidx,
    const float* __restrict__ enorm, const float* __restrict__ esgn,
    int* __restrict__ bcur0, int2* __restrict__ recs, int n_edges)
{
    int t = blockIdx.x * NB + threadIdx.x;
    int e0 = t * EPT;
    if (e0 + EPT <= n_edges) {
        int4   tn = *(const int4*)(tidx + e0);
        int4   sn = *(const int4*)(sidx + e0);
        float4 nw = *(const float4*)(enorm + e0);
        float4 sw = *(const float4*)(esgn + e0);
        DO_EDGE(tn.x, sn.x, nw.x * sw.x);
        DO_EDGE(tn.y, sn.y, nw.y * sw.y);
        DO_EDGE(tn.z, sn.z, nw.z * sw.z);
        DO_EDGE(tn.w, sn.w, nw.w * sw.w);
    } else {
        for (int e = e0; e < n_edges; ++e) {
            int tn = tidx[e];
            int sn = sidx[e];
            float w = enorm[e] * esgn[e];
            DO_EDGE(tn, sn, w);
        }
    }
}

// Fused node-sort + accumulate, one block per bucket (128 nodes).
// Normal path: bucket records staged & node-sorted entirely in LDS, then
// 8 lanes/node x float4 accumulate with 4-deep unroll (no atomics).
// Overflow path (cnt > CAP, adversarial only): atomic accumulate.
__global__ __launch_bounds__(1024) void bucket_accum(
    const float* __restrict__ input, const int2* __restrict__ recs,
    const int* __restrict__ bbase, float* __restrict__ out, int n_nodes)
{
    __shared__ int2 srec[CAP];             // 48 KB
    __shared__ int lcnt[SPAN];
    __shared__ int lbeg[SPAN];
    __shared__ int lcur[SPAN];
    int b = blockIdx.x;
    int t = threadIdx.x;
    int bstart = bbase[b], bend = bbase[b + 1];
    int base_node = b << SPAN_SHIFT;

    if (bend - bstart <= CAP) {
        if (t < SPAN) lcnt[t] = 0;
        __syncthreads();
        // node histogram
        for (int i = bstart + t; i < bend; i += 1024)
            atomicAdd(&lcnt[recs[i].x & (SPAN - 1)], 1);
        __syncthreads();
        // exclusive scan over SPAN=128 (masked H-S, uniform barriers)
        int c = (t < SPAN) ? lcnt[t] : 0;
        if (t < SPAN) lbeg[t] = c;
        __syncthreads();
        for (int off = 1; off < SPAN; off <<= 1) {
            int v = (t < SPAN && t >= off) ? lbeg[t - off] : 0;
            __syncthreads();
            if (t < SPAN) lbeg[t] += v;
            __syncthreads();
        }
        if (t < SPAN) {
            int excl = lbeg[t] - c;
            lbeg[t] = excl;
            lcur[t] = excl;
        }
        __syncthreads();
        // scatter into LDS, node-sorted
        for (int i = bstart + t; i < bend; i += 1024) {
            int2 r = recs[i];
            int pos = atomicAdd(&lcur[r.x & (SPAN - 1)], 1);
            srec[pos] = r;
        }
        __syncthreads();
        // accumulate: 8 lanes per node, float4 per lane, 4-deep unroll
        int node = t >> 3;
        int lane = t & 7;
        int beg = lbeg[node];
        int end = beg + lcnt[node];
        float4 acc = make_float4(0.f, 0.f, 0.f, 0.f);
        int i = beg;
        for (; i + 3 < end; i += 4) {
            int2 r0 = srec[i];
            int2 r1 = srec[i + 1];
            int2 r2 = srec[i + 2];
            int2 r3 = srec[i + 3];
            float4 v0 = ((const float4*)(input + (size_t)(((unsigned)r0.x) >> SPAN_SHIFT) * 32))[lane];
            float4 v1 = ((const float4*)(input + (size_t)(((unsigned)r1.x) >> SPAN_SHIFT) * 32))[lane];
            float4 v2 = ((const float4*)(input + (size_t)(((unsigned)r2.x) >> SPAN_SHIFT) * 32))[lane];
            float4 v3 = ((const float4*)(input + (size_t)(((unsigned)r3.x) >> SPAN_SHIFT) * 32))[lane];
            float w0 = __int_as_float(r0.y);
            float w1 = __int_as_float(r1.y);
            float w2 = __int_as_float(r2.y);
            float w3 = __int_as_float(r3.y);
            acc.x = fmaf(w0, v0.x, acc.x);
            acc.y = fmaf(w0, v0.y, acc.y);
            acc.z = fmaf(w0, v0.z, acc.z);
            acc.w = fmaf(w0, v0.w, acc.w);
            acc.x = fmaf(w1, v1.x, acc.x);
            acc.y = fmaf(w1, v1.y, acc.y);
            acc.z = fmaf(w1, v1.z, acc.z);
            acc.w = fmaf(w1, v1.w, acc.w);
            acc.x = fmaf(w2, v2.x, acc.x);
            acc.y = fmaf(w2, v2.y, acc.y);
            acc.z = fmaf(w2, v2.z, acc.z);
            acc.w = fmaf(w2, v2.w, acc.w);
            acc.x = fmaf(w3, v3.x, acc.x);
            acc.y = fmaf(w3, v3.y, acc.y);
            acc.z = fmaf(w3, v3.z, acc.z);
            acc.w = fmaf(w3, v3.w, acc.w);
        }
        for (; i < end; ++i) {
            int2 r = srec[i];
            float w = __int_as_float(r.y);
            float4 v = ((const float4*)(input + (size_t)(((unsigned)r.x) >> SPAN_SHIFT) * 32))[lane];
            acc.x = fmaf(w, v.x, acc.x);
            acc.y = fmaf(w, v.y, acc.y);
            acc.z = fmaf(w, v.z, acc.z);
            acc.w = fmaf(w, v.w, acc.w);
        }
        int gnode = base_node + node;
        if (gnode < n_nodes)
            ((float4*)(out + (size_t)gnode * 32))[lane] = acc;
    } else {
        // overflow fallback (correctness only; ~never taken on random data)
        for (int i = t; i < SPAN * 32; i += 1024) {
            int gn = base_node + (i >> 5);
            if (gn < n_nodes) out[(size_t)gn * 32 + (i & 31)] = 0.f;
        }
        __syncthreads();
        for (int i = bstart + t; i < bend; i += 1024) {
            int2 r = recs[i];
            float w = __int_as_float(r.y);
            int s = (int)(((unsigned)r.x) >> SPAN_SHIFT);
            int gn = base_node + (r.x & (SPAN - 1));
            if (gn < n_nodes)
                for (int j = 0; j < 32; ++j)
                    atomicAdd(&out[(size_t)gn * 32 + j], w * input[(size_t)s * 32 + j]);
        }
    }
}

// Last-resort fallback (R3): direct atomic scatter.
__global__ __launch_bounds__(NB) void graphconv_scatter(
    const float* __restrict__ input, const int* __restrict__ sidx,
    const int* __restrict__ tidx, const float* __restrict__ enorm,
    const float* __restrict__ esgn, float* __restrict__ out, int n_edges)
{
    int t = blockIdx.x * NB + threadIdx.x;
    int e = t >> 3;
    int sub = t & 7;
    if (e >= n_edges) return;
    int s = sidx[e];
    int d = tidx[e];
    float w = enorm[e] * esgn[e];
    const float4* src = (const float4*)(input + (size_t)s * 32);
    float4 v = src[sub];
    float* op = out + (size_t)d * 32 + sub * 4;
    atomicAdd(op + 0, v.x * w);
    atomicAdd(op + 1, v.y * w);
    atomicAdd(op + 2, v.z * w);
    atomicAdd(op + 3, v.w * w);
}

extern "C" void kernel_launch(void* const* d_in, const int* in_sizes, int n_in,
                              void* d_out, int out_size, void* d_ws, size_t ws_size,
                              hipStream_t stream) {
    const float* input = (const float*)d_in[0];
    const int*   eidx  = (const int*)d_in[1];   // int64 in reference -> int32 here
    const float* enorm = (const float*)d_in[2];
    const float* esgn  = (const float*)d_in[3];
    float*       out   = (float*)d_out;

    int n_edges = in_sizes[1] / 2;             // eidx is (2, n_edges)
    int n_nodes = in_sizes[0] / 32;            // input is (n_nodes, 32)
    const int* sidx = eidx;
    const int* tidx = eidx + n_edges;

    int K = (n_nodes + SPAN - 1) >> SPAN_SHIFT;   // 782 for 100K nodes

    // Workspace: recs[E int2] | bcnt[KMAX] | bcur0[KMAX] | bbase[KMAX+1]
    size_t need = (size_t)n_edges * 8 + (3 * KMAX + 1) * 4;

    if (ws_size >= need && K <= KMAX) {
        int2* recs  = (int2*)d_ws;
        int*  bcnt  = (int*)(recs + n_edges);
        int*  bcur0 = bcnt + KMAX;
        int*  bbase = bcur0 + KMAX;

        hipMemsetAsync(bcnt, 0, KMAX * sizeof(int), stream);

        bhist_kernel  <<<1024, NB,   0, stream>>>(tidx, bcnt, n_edges);
        bscan_kernel  <<<1,    KMAX, 0, stream>>>(bcnt, bbase, bcur0, K);
        int nthr = (n_edges + EPT - 1) / EPT;
        int pg = (nthr + NB - 1) / NB;
        partition_flat<<<pg,   NB,   0, stream>>>(sidx, tidx, enorm, esgn,
                                                  bcur0, recs, n_edges);
        bucket_accum  <<<K,    1024, 0, stream>>>(input, recs, bbase,
                                                  out, n_nodes);
    } else {
        hipMemsetAsync(d_out, 0, (size_t)out_size * sizeof(float), stream);
        size_t threads_total = (size_t)n_edges * 8;
        int grid = (int)((threads_total + NB - 1) / NB);
        graphconv_scatter<<<grid, NB, 0, stream>>>(input, sidx, tidx, enorm, esgn,
                                                   out, n_edges);
    }
}

// Round 7
// 201.450 us; speedup vs baseline: 4.5674x; 4.5674x over previous
//
#include <hip/hip_runtime.h>

// GraphConv: out[t] += input[s] * (esgn*enorm), 3.2M edges, 100K nodes, D=32 fp32.
// Round 18: R17's flat partition (749us, occ 72%, VALU 0.1%) proved the
// per-bucket GLOBAL cursor is the serialized resource: 3.2M returning atomics
// over 782 addresses ~= 4090 serial round-trips x ~440cyc. (Retroactively,
// R15/R16's ~544 reservations/cursor ~= 100us explains their 96-123us floor.)
// Fix: DETERMINISTIC placement, zero global atomics. Edges split into G=256
// chunks; cnt[g][b] matrix (hist, LDS) -> per-bucket column scan (scan1) ->
// bucket base scan (bscan) -> scatter: block g seeds gbase[b]=bbase[b]+pref
// in LDS, ranks via LDS atomic (~16 collisions per (g,b)), direct store.
// memset deleted. Pipeline: hist -> scan1 -> bscan -> scatter -> bucket_accum.

#define G    256          // edge chunks / scatter blocks
#define KMAX 1024         // max buckets (span 128 -> n_nodes <= 131072)
#define SPAN_SHIFT 7
#define SPAN 128
#define CAP  6144         // bucket_accum LDS record capacity (48KB)
#define NB   256

// Per-chunk histogram: cnt[g*KMAX + b]. Coalesced matrix write, no atomics
// beyond LDS.
__global__ __launch_bounds__(1024) void hist_kernel(
    const int* __restrict__ tidx, int* __restrict__ cnt,
    int n_edges, int epb, int vec)
{
    __shared__ int lh[KMAX];
    int g = blockIdx.x, t = threadIdx.x;
    lh[t] = 0;
    __syncthreads();
    int beg = g * epb;
    int lim = beg + epb; if (lim > n_edges) lim = n_edges;
    if (vec) {
        int nq = (lim > beg) ? ((lim - beg) >> 2) : 0;
        for (int q = t; q < nq; q += 1024) {
            int4 tn = *(const int4*)(tidx + beg + q * 4);
            atomicAdd(&lh[tn.x >> SPAN_SHIFT], 1);
            atomicAdd(&lh[tn.y >> SPAN_SHIFT], 1);
            atomicAdd(&lh[tn.z >> SPAN_SHIFT], 1);
            atomicAdd(&lh[tn.w >> SPAN_SHIFT], 1);
        }
        for (int e = beg + (nq << 2) + t; e < lim; e += 1024)
            atomicAdd(&lh[tidx[e] >> SPAN_SHIFT], 1);
    } else {
        for (int e = beg + t; e < lim; e += 1024)
            atomicAdd(&lh[tidx[e] >> SPAN_SHIFT], 1);
    }
    __syncthreads();
    cnt[g * KMAX + t] = lh[t];
}

// Per-bucket exclusive scan over the G chunk counts -> pref[g][b], tot[b].
__global__ __launch_bounds__(G) void scan1_kernel(
    const int* __restrict__ cnt, int* __restrict__ pref, int* __restrict__ tot)
{
    __shared__ int part[G];
    int b = blockIdx.x, t = threadIdx.x;
    int c = cnt[t * KMAX + b];
    part[t] = c;
    __syncthreads();
    for (int off = 1; off < G; off <<= 1) {
        int v = (t >= off) ? part[t - off] : 0;
        __syncthreads();
        part[t] += v;
        __syncthreads();
    }
    pref[t * KMAX + b] = part[t] - c;
    if (t == G - 1) tot[b] = part[t];
}

// Exclusive scan over KMAX bucket totals -> bbase[0..KMAX] (all entries
// written; entries >= K act as end sentinels since tot[b>=K] == 0).
__global__ __launch_bounds__(KMAX) void bscan_kernel(
    const int* __restrict__ tot, int* __restrict__ bbase)
{
    __shared__ int part[KMAX];
    int t = threadIdx.x;
    int c = tot[t];
    part[t] = c;
    __syncthreads();
    for (int off = 1; off < KMAX; off <<= 1) {
        int v = (t >= off) ? part[t - off] : 0;
        __syncthreads();
        part[t] += v;
        __syncthreads();
    }
    bbase[t] = part[t] - c;
    if (t == KMAX - 1) bbase[KMAX] = part[t];
}

// Deterministic scatter: block g owns chunk g; position = gbase[b] + LDS rank.
// No global atomics; one pass.
__global__ __launch_bounds__(1024) void scatter_kernel(
    const int* __restrict__ sidx, const int* __restrict__ tidx,
    const float* __restrict__ enorm, const float* __restrict__ esgn,
    const int* __restrict__ bbase, const int* __restrict__ pref,
    int2* __restrict__ recs, int n_edges, int epb, int vec)
{
    __shared__ int gbase[KMAX];
    __shared__ int lh[KMAX];
    int g = blockIdx.x, t = threadIdx.x;
    gbase[t] = bbase[t] + pref[g * KMAX + t];
    lh[t] = 0;
    __syncthreads();
    int beg = g * epb;
    int lim = beg + epb; if (lim > n_edges) lim = n_edges;

    #define SCAT_EDGE(tn_, sn_, w_) {                                        \
        int b_ = (tn_) >> SPAN_SHIFT;                                        \
        int rank_ = atomicAdd(&lh[b_], 1);                                   \
        unsigned rec_ = ((unsigned)(sn_) << SPAN_SHIFT) |                    \
                        (unsigned)((tn_) & (SPAN - 1));                      \
        recs[gbase[b_] + rank_] = make_int2((int)rec_, __float_as_int(w_)); }

    if (vec) {
        int nq = (lim > beg) ? ((lim - beg) >> 2) : 0;
        for (int q = t; q < nq; q += 1024) {
            int e = beg + q * 4;
            int4   tn = *(const int4*)(tidx + e);
            int4   sn = *(const int4*)(sidx + e);
            float4 nw = *(const float4*)(enorm + e);
            float4 sw = *(const float4*)(esgn + e);
            SCAT_EDGE(tn.x, sn.x, nw.x * sw.x);
            SCAT_EDGE(tn.y, sn.y, nw.y * sw.y);
            SCAT_EDGE(tn.z, sn.z, nw.z * sw.z);
            SCAT_EDGE(tn.w, sn.w, nw.w * sw.w);
        }
        for (int e = beg + (nq << 2) + t; e < lim; e += 1024) {
            int tn = tidx[e]; int sn = sidx[e];
            float w = enorm[e] * esgn[e];
            SCAT_EDGE(tn, sn, w);
        }
    } else {
        for (int e = beg + t; e < lim; e += 1024) {
            int tn = tidx[e]; int sn = sidx[e];
            float w = enorm[e] * esgn[e];
            SCAT_EDGE(tn, sn, w);
        }
    }
    #undef SCAT_EDGE
}

// Fused node-sort + accumulate, one block per bucket (128 nodes). Verified
// R15-R17. Normal path: records staged & node-sorted in LDS, then 8 lanes/node
// float4 accumulate, 4-deep unroll. Overflow path: atomic accumulate.
__global__ __launch_bounds__(1024) void bucket_accum(
    const float* __restrict__ input, const int2* __restrict__ recs,
    const int* __restrict__ bbase, float* __restrict__ out, int n_nodes)
{
    __shared__ int2 srec[CAP];             // 48 KB
    __shared__ int lcnt[SPAN];
    __shared__ int lbeg[SPAN];
    __shared__ int lcur[SPAN];
    int b = blockIdx.x;
    int t = threadIdx.x;
    int bstart = bbase[b], bend = bbase[b + 1];
    int base_node = b << SPAN_SHIFT;

    if (bend - bstart <= CAP) {
        if (t < SPAN) lcnt[t] = 0;
        __syncthreads();
        for (int i = bstart + t; i < bend; i += 1024)
            atomicAdd(&lcnt[recs[i].x & (SPAN - 1)], 1);
        __syncthreads();
        int c = (t < SPAN) ? lcnt[t] : 0;
        if (t < SPAN) lbeg[t] = c;
        __syncthreads();
        for (int off = 1; off < SPAN; off <<= 1) {
            int v = (t < SPAN && t >= off) ? lbeg[t - off] : 0;
            __syncthreads();
            if (t < SPAN) lbeg[t] += v;
            __syncthreads();
        }
        if (t < SPAN) {
            int excl = lbeg[t] - c;
            lbeg[t] = excl;
            lcur[t] = excl;
        }
        __syncthreads();
        for (int i = bstart + t; i < bend; i += 1024) {
            int2 r = recs[i];
            int pos = atomicAdd(&lcur[r.x & (SPAN - 1)], 1);
            srec[pos] = r;
        }
        __syncthreads();
        int node = t >> 3;
        int lane = t & 7;
        int beg = lbeg[node];
        int end = beg + lcnt[node];
        float4 acc = make_float4(0.f, 0.f, 0.f, 0.f);
        int i = beg;
        for (; i + 3 < end; i += 4) {
            int2 r0 = srec[i];
            int2 r1 = srec[i + 1];
            int2 r2 = srec[i + 2];
            int2 r3 = srec[i + 3];
            float4 v0 = ((const float4*)(input + (size_t)(((unsigned)r0.x) >> SPAN_SHIFT) * 32))[lane];
            float4 v1 = ((const float4*)(input + (size_t)(((unsigned)r1.x) >> SPAN_SHIFT) * 32))[lane];
            float4 v2 = ((const float4*)(input + (size_t)(((unsigned)r2.x) >> SPAN_SHIFT) * 32))[lane];
            float4 v3 = ((const float4*)(input + (size_t)(((unsigned)r3.x) >> SPAN_SHIFT) * 32))[lane];
            float w0 = __int_as_float(r0.y);
            float w1 = __int_as_float(r1.y);
            float w2 = __int_as_float(r2.y);
            float w3 = __int_as_float(r3.y);
            acc.x = fmaf(w0, v0.x, acc.x);
            acc.y = fmaf(w0, v0.y, acc.y);
            acc.z = fmaf(w0, v0.z, acc.z);
            acc.w = fmaf(w0, v0.w, acc.w);
            acc.x = fmaf(w1, v1.x, acc.x);
            acc.y = fmaf(w1, v1.y, acc.y);
            acc.z = fmaf(w1, v1.z, acc.z);
            acc.w = fmaf(w1, v1.w, acc.w);
            acc.x = fmaf(w2, v2.x, acc.x);
            acc.y = fmaf(w2, v2.y, acc.y);
            acc.z = fmaf(w2, v2.z, acc.z);
            acc.w = fmaf(w2, v2.w, acc.w);
            acc.x = fmaf(w3, v3.x, acc.x);
            acc.y = fmaf(w3, v3.y, acc.y);
            acc.z = fmaf(w3, v3.z, acc.z);
            acc.w = fmaf(w3, v3.w, acc.w);
        }
        for (; i < end; ++i) {
            int2 r = srec[i];
            float w = __int_as_float(r.y);
            float4 v = ((const float4*)(input + (size_t)(((unsigned)r.x) >> SPAN_SHIFT) * 32))[lane];
            acc.x = fmaf(w, v.x, acc.x);
            acc.y = fmaf(w, v.y, acc.y);
            acc.z = fmaf(w, v.z, acc.z);
            acc.w = fmaf(w, v.w, acc.w);
        }
        int gnode = base_node + node;
        if (gnode < n_nodes)
            ((float4*)(out + (size_t)gnode * 32))[lane] = acc;
    } else {
        for (int i = t; i < SPAN * 32; i += 1024) {
            int gn = base_node + (i >> 5);
            if (gn < n_nodes) out[(size_t)gn * 32 + (i & 31)] = 0.f;
        }
        __syncthreads();
        for (int i = bstart + t; i < bend; i += 1024) {
            int2 r = recs[i];
            float w = __int_as_float(r.y);
            int s = (int)(((unsigned)r.x) >> SPAN_SHIFT);
            int gn = base_node + (r.x & (SPAN - 1));
            if (gn < n_nodes)
                for (int j = 0; j < 32; ++j)
                    atomicAdd(&out[(size_t)gn * 32 + j], w * input[(size_t)s * 32 + j]);
        }
    }
}

// Last-resort fallback (R3): direct atomic scatter.
__global__ __launch_bounds__(NB) void graphconv_scatter(
    const float* __restrict__ input, const int* __restrict__ sidx,
    const int* __restrict__ tidx, const float* __restrict__ enorm,
    const float* __restrict__ esgn, float* __restrict__ out, int n_edges)
{
    int t = blockIdx.x * NB + threadIdx.x;
    int e = t >> 3;
    int sub = t & 7;
    if (e >= n_edges) return;
    int s = sidx[e];
    int d = tidx[e];
    float w = enorm[e] * esgn[e];
    const float4* src = (const float4*)(input + (size_t)s * 32);
    float4 v = src[sub];
    float* op = out + (size_t)d * 32 + sub * 4;
    atomicAdd(op + 0, v.x * w);
    atomicAdd(op + 1, v.y * w);
    atomicAdd(op + 2, v.z * w);
    atomicAdd(op + 3, v.w * w);
}

extern "C" void kernel_launch(void* const* d_in, const int* in_sizes, int n_in,
                              void* d_out, int out_size, void* d_ws, size_t ws_size,
                              hipStream_t stream) {
    const float* input = (const float*)d_in[0];
    const int*   eidx  = (const int*)d_in[1];   // int64 in reference -> int32 here
    const float* enorm = (const float*)d_in[2];
    const float* esgn  = (const float*)d_in[3];
    float*       out   = (float*)d_out;

    int n_edges = in_sizes[1] / 2;             // eidx is (2, n_edges)
    int n_nodes = in_sizes[0] / 32;            // input is (n_nodes, 32)
    const int* sidx = eidx;
    const int* tidx = eidx + n_edges;

    int K = (n_nodes + SPAN - 1) >> SPAN_SHIFT;   // 782 for 100K nodes

    // Workspace: recs[E int2] | cnt[G*KMAX] | pref[G*KMAX] | tot[KMAX] | bbase[KMAX+1]
    size_t need = (size_t)n_edges * 8 +
                  ((size_t)2 * G * KMAX + 2 * KMAX + 1) * 4;

    if (ws_size >= need && K <= KMAX) {
        int2* recs  = (int2*)d_ws;
        int*  cnt   = (int*)(recs + n_edges);
        int*  pref  = cnt + (size_t)G * KMAX;
        int*  tot   = pref + (size_t)G * KMAX;
        int*  bbase = tot + KMAX;

        // chunk size: multiple of 4 so vector loads stay 16B-aligned
        int epb = ((n_edges + G - 1) / G + 3) & ~3;
        int vec = ((n_edges & 3) == 0 &&
                   (((uintptr_t)tidx | (uintptr_t)sidx |
                     (uintptr_t)enorm | (uintptr_t)esgn) & 15) == 0) ? 1 : 0;

        hist_kernel   <<<G,    1024, 0, stream>>>(tidx, cnt, n_edges, epb, vec);
        scan1_kernel  <<<KMAX, G,    0, stream>>>(cnt, pref, tot);
        bscan_kernel  <<<1,    KMAX, 0, stream>>>(tot, bbase);
        scatter_kernel<<<G,    1024, 0, stream>>>(sidx, tidx, enorm, esgn,
                                                  bbase, pref, recs,
                                                  n_edges, epb, vec);
        bucket_accum  <<<K,    1024, 0, stream>>>(input, recs, bbase,
                                                  out, n_nodes);
    } else {
        hipMemsetAsync(d_out, 0, (size_t)out_size * sizeof(float), stream);
        size_t threads_total = (size_t)n_edges * 8;
        int grid = (int)((threads_total + NB - 1) / NB);
        graphconv_scatter<<<grid, NB, 0, stream>>>(input, sidx, tidx, enorm, esgn,
                                                   out, n_edges);
    }
}